// Round 10
// baseline (240.314 us; speedup 1.0000x reference)
//
#include <hip/hip_runtime.h>
#include <hip/hip_bf16.h>
#include <stdint.h>

typedef __bf16 bf16;
typedef __bf16 bf16x8 __attribute__((ext_vector_type(8)));
typedef __bf16 bf16x4 __attribute__((ext_vector_type(4)));
typedef short  s16x4  __attribute__((ext_vector_type(4)));
typedef short  s16x8  __attribute__((ext_vector_type(8)));
typedef float  f32x4  __attribute__((ext_vector_type(4)));

#define N_B 4
#define N_T 2048
#define N_D 768
#define N_H 12
#define N_DH 64
#define M_TOT (N_B * N_T)   // 8192

// async global->LDS, 16 bytes per lane. LDS dest must be base + lane*16.
__device__ __forceinline__ void async_copy16(const bf16* g, bf16* l) {
    __builtin_amdgcn_global_load_lds(
        (const __attribute__((address_space(1))) unsigned int*)g,
        (__attribute__((address_space(3))) unsigned int*)l,
        16, 0, 0);
}

// fused fp32 -> bf16 convert for three arrays (each size % 1024 == 0, so
// every 256-thread block stays within one segment)
__launch_bounds__(256)
__global__ void f2bf3(const float* __restrict__ a, bf16* __restrict__ oa, int na,
                      const float* __restrict__ b, bf16* __restrict__ ob, int nb,
                      const float* __restrict__ c, bf16* __restrict__ oc) {
    int i = (blockIdx.x * 256 + threadIdx.x) * 4;
    const float* src; bf16* dst;
    if (i < na)            { src = a; dst = oa; }
    else if (i < na + nb)  { src = b; dst = ob; i -= na; }
    else                   { src = c; dst = oc; i -= na + nb; }
    const float4 v = *(const float4*)(src + i);
    dst[i]     = (bf16)v.x;
    dst[i + 1] = (bf16)v.y;
    dst[i + 2] = (bf16)v.z;
    dst[i + 3] = (bf16)v.w;
}

// ---------------------------------------------------------------------------
// GEMM core: C[m,n] = sum_k A[m,k] * Bt[n,k]  (both K-contiguous, bf16)
// 128x128 tile, BK=32, 256 threads (4 waves, 2x2 of 64x64), 16x16x32 MFMA.
// ---------------------------------------------------------------------------
#define GEMM_CORE(A_PTR, B_PTR, KDIM)                                          \
    __shared__ bf16 lsA[128 * 32];                                             \
    __shared__ bf16 lsB[128 * 32];                                             \
    const int m0 = blockIdx.x * 128;                                           \
    const int n0 = blockIdx.y * 128;                                           \
    const int t  = threadIdx.x;                                                \
    const int w  = t >> 6, l = t & 63;                                         \
    const int wm = w & 1, wn = w >> 1;                                         \
    const int lr = l & 15, lq = l >> 4;                                        \
    f32x4 acc[4][4] = {};                                                      \
    const bf16* Ab = (A_PTR) + (size_t)(m0 + (t >> 2)) * (KDIM) + (t & 3) * 8; \
    const bf16* Bb = (B_PTR) + (size_t)(n0 + (t >> 2)) * (KDIM) + (t & 3) * 8; \
    bf16* lA = lsA + t * 8;                                                    \
    bf16* lB = lsB + t * 8;                                                    \
    for (int k0 = 0; k0 < (KDIM); k0 += 32) {                                  \
        __syncthreads();                                                       \
        async_copy16(Ab + k0, lA);                                             \
        async_copy16(Ab + (size_t)64 * (KDIM) + k0, lA + 2048);                \
        async_copy16(Bb + k0, lB);                                             \
        async_copy16(Bb + (size_t)64 * (KDIM) + k0, lB + 2048);                \
        __syncthreads();                                                       \
        bf16x8 af[4], bfr[4];                                                  \
        for (int i = 0; i < 4; i++) {                                          \
            af[i]  = *(const bf16x8*)(lsA + (wm * 64 + i * 16 + lr) * 32 + lq * 8); \
            bfr[i] = *(const bf16x8*)(lsB + (wn * 64 + i * 16 + lr) * 32 + lq * 8); \
        }                                                                      \
        for (int i = 0; i < 4; i++)                                            \
            for (int j = 0; j < 4; j++)                                        \
                acc[i][j] = __builtin_amdgcn_mfma_f32_16x16x32_bf16(           \
                    af[i], bfr[j], acc[i][j], 0, 0, 0);                        \
    }

// QKV projection: Xb * Wb^T + b_qkv.
// Q: [B,H,T,64] pre-scaled by 0.125*log2(e) (softmax in base-2);
// K: [B,H,T,64]; V: transposed [B,H,64,T] with keys PERMUTED inside each
// 64-token tile: idx(k) = (r>>2)*16 + kc*4 + (r&3), kc=k>>4, r=k&15 — so a
// single b128 LDS read in attn yields A-frags for two kc blocks.
__launch_bounds__(256)
__global__ void gemm_qkv(const bf16* __restrict__ X, const bf16* __restrict__ W,
                         const float* __restrict__ bias,
                         bf16* __restrict__ Q, bf16* __restrict__ K,
                         bf16* __restrict__ Vt) {
    GEMM_CORE(X, W, 768)
    // epilogue: C/D layout col=lane&15, row=(lane>>4)*4+reg
    for (int i = 0; i < 4; i++) {
        const int rowb = m0 + wm * 64 + i * 16 + lq * 4;
        const int b_ = rowb >> 11, tt = rowb & 2047;   // 128-tiles never straddle batch
        for (int j = 0; j < 4; j++) {
            const int col   = n0 + wn * 64 + j * 16 + lr;
            const int which = col / 768;
            const int rem   = col - which * 768;
            const int h     = rem >> 6, d = rem & 63;
            const float bv  = bias[col];
            if (which == 2) {
                // V^T with in-tile key permutation (tt multiple of 4)
                const int tile = tt >> 6, kl = tt & 63;
                const int kc = kl >> 4, r = kl & 15;
                const int idx = ((r >> 2) << 4) + (kc << 2);   // + (r&3)=0..3
                bf16x4 v4;
                for (int r2 = 0; r2 < 4; r2++) v4[r2] = (bf16)(acc[i][j][r2] + bv);
                *(bf16x4*)(Vt + ((size_t)((b_ * N_H + h) * 64 + d)) * 2048
                           + tile * 64 + idx) = v4;
            } else {
                bf16* dst = (which == 0) ? Q : K;
                const float sc = (which == 0) ? 0.18033688f : 1.0f;  // 1/8 * log2(e)
                for (int r2 = 0; r2 < 4; r2++)
                    dst[(size_t)(((b_ * N_H + h) << 11) + tt + r2) * 64 + d] =
                        (bf16)((acc[i][j][r2] + bv) * sc);
            }
        }
    }
}

// Output projection: Ob[8192x768] * Wpb[768x768]^T + b_proj -> out fp32
__launch_bounds__(256)
__global__ void gemm_proj(const bf16* __restrict__ O, const bf16* __restrict__ W,
                          const float* __restrict__ bias, float* __restrict__ out) {
    GEMM_CORE(O, W, 768)
    for (int i = 0; i < 4; i++) {
        const int rowb = m0 + wm * 64 + i * 16 + lq * 4;
        for (int j = 0; j < 4; j++) {
            const int col  = n0 + wn * 64 + j * 16 + lr;
            const float bv = bias[col];
            for (int r = 0; r < 4; r++)
                out[(size_t)(rowb + r) * 768 + col] = acc[i][j][r] + bv;
        }
    }
}

// ---------------------------------------------------------------------------
// Flash attention: transposed formulation, double-buffered LDS K/V tiles,
// KEY-SPLIT x 2 q-sets. 512 thr = 8 waves; wave w = q-group (w&3, 32 q as
// 2 frag sets) x key-half (w>>2, 32 keys of each 64-key tile) -> 128 q/block.
// Each wave reads only HALF of each staged K/V tile, amortized over 2 q-sets
// (CU-level LDS read pipe is the binding resource: R8 spent ~61us there).
// Fixed-shift softmax (p = exp2(s), no running max) => O/l associative over
// keys; halves merge once at the end via a 32KB fp32 LDS exchange aliasing
// the dead staging buffers (exact).
// S^T = K Q^T (16x16x32): P^T lands in C-layout == B-operand of 16x16x16.
// O^T = V^T P^T in C-layout (rows=d, cols=q); l via ones-MFMA (matrix pipe).
// Grid: flat 768, XCD-swizzled: each XCD owns 6 whole heads (3MB K/V in L2).
// ---------------------------------------------------------------------------
__launch_bounds__(512)
__global__ void attn(const bf16* __restrict__ Q, const bf16* __restrict__ K,
                     const bf16* __restrict__ Vt, bf16* __restrict__ O) {
    __shared__ bf16 lsKV[4][64 * 64];    // [0..1]: K dbuf, [2..3]: V dbuf; 32 KB
    __shared__ float lsl[128];           // partial-l exchange
    const int bid = blockIdx.x;
    const int xcd = bid & 7, slot = bid >> 3;
    const int bh  = xcd + 8 * (slot >> 4);   // 0..47, 6 heads per XCD
    const int qt  = slot & 15;               // 0..15
    const int t = threadIdx.x, w = t >> 6, l = t & 63;
    const int lr = l & 15, lq = l >> 4;
    const int g  = w & 3;                    // q-group (32 q, 2 sets)
    const int kh = w >> 2;                   // key-half (32 keys per tile)
    const bf16* Qh  = Q  + (size_t)bh * N_T * 64;
    const bf16* Kh  = K  + (size_t)bh * N_T * 64;
    const bf16* Vth = Vt + (size_t)bh * 64 * N_T;
    const int q0 = qt * 128 + g * 32;        // wave's q base (32 rows)

    // staging: thread t stages one 16B K chunk + one 16B V chunk per kt.
    const int sr = t >> 3;                   // 0..63
    const int sp = t & 7;                    // 0..7
    const int scn = sp ^ (sr & 7);           // XOR swizzle on source 16B unit

    // Q fragments (B-operand, n=q=lr, k=d), 2 sets of 16 q
    bf16x8 qf[2][2];
    for (int s = 0; s < 2; s++)
        for (int ks = 0; ks < 2; ks++)
            qf[s][ks] = *(const bf16x8*)(Qh + (size_t)(q0 + s * 16 + lr) * 64 + ks * 32 + lq * 8);

    f32x4 oacc[2][4] = {};                   // partial O^T[d][q=lr] per set
    f32x4 lacc[2] = {};                      // partial l(q) via ones-MFMA
    const s16x4 ones = {0x3F80, 0x3F80, 0x3F80, 0x3F80};  // bf16 1.0 x4

    // prologue: stage tile 0 into buffer 0
    async_copy16(Kh  + (size_t)sr * 64 + scn * 8,   lsKV[0] + t * 8);
    async_copy16(Vth + (size_t)sr * 2048 + scn * 8, lsKV[2] + t * 8);

    for (int kt = 0; kt < 32; kt++) {
        const int cur = kt & 1;
        __syncthreads();   // drains buf[cur] copies; prev reads of buf[cur^1] done

        if (kt < 31) {     // prefetch next tile into the other buffer
            async_copy16(Kh  + (size_t)((kt + 1) * 64 + sr) * 64 + scn * 8,
                         lsKV[cur ^ 1] + t * 8);
            async_copy16(Vth + (size_t)sr * 2048 + (kt + 1) * 64 + scn * 8,
                         lsKV[2 + (cur ^ 1)] + t * 8);
        }

        // ---- S^T = K Q^T over this wave's 32-key half, both q-sets ----
        f32x4 sacc[2][2] = {};               // [set][ki]; key = kh*32+ki*16+lq*4+r
        for (int ks = 0; ks < 2; ks++)
            for (int ki = 0; ki < 2; ki++) {
                const int row = kh * 32 + ki * 16 + lr;
                bf16x8 kf = *(const bf16x8*)(lsKV[cur] + row * 64 + ((ks * 4 + lq) ^ (lr & 7)) * 8);
                for (int s = 0; s < 2; s++)
                    sacc[s][ki] = __builtin_amdgcn_mfma_f32_16x16x32_bf16(
                        kf, qf[s][ks], sacc[s][ki], 0, 0, 0);
            }

        // ---- p = exp2(s); pack bf16 ----
        s16x4 pbf[2][2];
        for (int s = 0; s < 2; s++)
            for (int ki = 0; ki < 2; ki++) {
                bf16x4 pb;
                for (int r = 0; r < 4; r++)
                    pb[r] = (bf16)exp2f(sacc[s][ki][r]);
                pbf[s][ki] = __builtin_bit_cast(s16x4, pb);
            }

        // ---- O^T += V^T P^T (one b128 V read serves both ki, both sets) ----
        for (int dj = 0; dj < 4; dj++) {
            const int row = dj * 16 + lr;
            const int unit = (2 * lq + kh) ^ (lr & 7);
            s16x8 vv = *(const s16x8*)(lsKV[2 + cur] + row * 64 + unit * 8);
            s16x4 vlo = __builtin_shufflevector(vv, vv, 0, 1, 2, 3);
            s16x4 vhi = __builtin_shufflevector(vv, vv, 4, 5, 6, 7);
            for (int s = 0; s < 2; s++) {
                oacc[s][dj] = __builtin_amdgcn_mfma_f32_16x16x16bf16_1k(
                    vlo, pbf[s][0], oacc[s][dj], 0, 0, 0);
                oacc[s][dj] = __builtin_amdgcn_mfma_f32_16x16x16bf16_1k(
                    vhi, pbf[s][1], oacc[s][dj], 0, 0, 0);
            }
        }
        for (int s = 0; s < 2; s++) {
            lacc[s] = __builtin_amdgcn_mfma_f32_16x16x16bf16_1k(ones, pbf[s][0], lacc[s], 0, 0, 0);
            lacc[s] = __builtin_amdgcn_mfma_f32_16x16x16bf16_1k(ones, pbf[s][1], lacc[s], 0, 0, 0);
        }
    }

    // ---- merge key-halves via fp32 exchange in the dead staging LDS ----
    __syncthreads();                         // all staging reads done; lsKV dead
    float* ex = (float*)lsKV;                // 8 (g,s) groups x 16 q x 64 d = 32 KB
    if (kh) {
        for (int s = 0; s < 2; s++) {
            for (int dj = 0; dj < 4; dj++)
                *(f32x4*)(ex + ((g * 2 + s) * 16 + lr) * 64 + dj * 16 + lq * 4) = oacc[s][dj];
            lsl[(g * 2 + s) * 16 + lr] = lacc[s][0];   // lq-replicated, same value
        }
    }
    __syncthreads();
    if (!kh) {
        const int b = bh / N_H, h = bh - b * N_H;
        for (int s = 0; s < 2; s++) {
            for (int dj = 0; dj < 4; dj++)
                oacc[s][dj] += *(const f32x4*)(ex + ((g * 2 + s) * 16 + lr) * 64 + dj * 16 + lq * 4);
            const float inv_l = 1.0f / (lacc[s][0] + lsl[(g * 2 + s) * 16 + lr]);
            const int tok = q0 + s * 16 + lr;
            bf16* Ob = O + ((size_t)b * N_T + tok) * N_D + h * 64;
            for (int dj = 0; dj < 4; dj++) {
                bf16x4 o4;
                for (int r = 0; r < 4; r++) o4[r] = (bf16)(oacc[s][dj][r] * inv_l);
                *(bf16x4*)(Ob + dj * 16 + lq * 4) = o4;
            }
        }
    }
}

extern "C" void kernel_launch(void* const* d_in, const int* in_sizes, int n_in,
                              void* d_out, int out_size, void* d_ws, size_t ws_size,
                              hipStream_t stream) {
    const float* x      = (const float*)d_in[0];
    const float* W_qkv  = (const float*)d_in[1];
    const float* b_qkv  = (const float*)d_in[2];
    const float* W_proj = (const float*)d_in[3];
    const float* b_proj = (const float*)d_in[4];
    float* out = (float*)d_out;

    char* ws = (char*)d_ws;
    const size_t n_x  = (size_t)M_TOT * N_D;        // 6291456
    const size_t n_wq = (size_t)3 * N_D * N_D;      // 1769472
    const size_t n_wp = (size_t)N_D * N_D;          // 589824
    const size_t sz_qkv = (size_t)N_B * N_H * N_T * N_DH * sizeof(bf16);  // 12.58 MB

    bf16* xb  = (bf16*)(ws);                 ws += n_x * sizeof(bf16);
    bf16* Wqb = (bf16*)(ws);                 ws += n_wq * sizeof(bf16);
    bf16* Wpb = (bf16*)(ws);                 ws += n_wp * sizeof(bf16);
    bf16* Qb  = (bf16*)(ws);                 ws += sz_qkv;
    bf16* Kb  = (bf16*)(ws);                 ws += sz_qkv;
    bf16* Vtb = (bf16*)(ws);                 ws += sz_qkv;
    bf16* Ob  = (bf16*)(ws);

    dim3 blk(256);
    f2bf3<<<dim3((int)((n_x + n_wq + n_wp) / 1024)), blk, 0, stream>>>(
        x, xb, (int)n_x, W_qkv, Wqb, (int)n_wq, W_proj, Wpb);

    gemm_qkv<<<dim3(M_TOT / 128, 2304 / 128), blk, 0, stream>>>(xb, Wqb, b_qkv, Qb, Kb, Vtb);
    attn<<<dim3(768), dim3(512), 0, stream>>>(Qb, Kb, Vtb, Ob);
    gemm_proj<<<dim3(M_TOT / 128, 768 / 128), blk, 0, stream>>>(Ob, Wpb, b_proj, out);
}

// Round 11
// 234.471 us; speedup vs baseline: 1.0249x; 1.0249x over previous
//
#include <hip/hip_runtime.h>
#include <hip/hip_bf16.h>
#include <stdint.h>

typedef __bf16 bf16;
typedef __bf16 bf16x8 __attribute__((ext_vector_type(8)));
typedef __bf16 bf16x4 __attribute__((ext_vector_type(4)));
typedef short  s16x4  __attribute__((ext_vector_type(4)));
typedef short  s16x8  __attribute__((ext_vector_type(8)));
typedef float  f32x4  __attribute__((ext_vector_type(4)));

#define N_B 4
#define N_T 2048
#define N_D 768
#define N_H 12
#define N_DH 64
#define M_TOT (N_B * N_T)   // 8192

// async global->LDS, 16 bytes per lane. LDS dest must be base + lane*16.
__device__ __forceinline__ void async_copy16(const bf16* g, bf16* l) {
    __builtin_amdgcn_global_load_lds(
        (const __attribute__((address_space(1))) unsigned int*)g,
        (__attribute__((address_space(3))) unsigned int*)l,
        16, 0, 0);
}

// fused fp32 -> bf16 convert for three arrays (each size % 1024 == 0, so
// every 256-thread block stays within one segment)
__launch_bounds__(256)
__global__ void f2bf3(const float* __restrict__ a, bf16* __restrict__ oa, int na,
                      const float* __restrict__ b, bf16* __restrict__ ob, int nb,
                      const float* __restrict__ c, bf16* __restrict__ oc) {
    int i = (blockIdx.x * 256 + threadIdx.x) * 4;
    const float* src; bf16* dst;
    if (i < na)            { src = a; dst = oa; }
    else if (i < na + nb)  { src = b; dst = ob; i -= na; }
    else                   { src = c; dst = oc; i -= na + nb; }
    const float4 v = *(const float4*)(src + i);
    dst[i]     = (bf16)v.x;
    dst[i + 1] = (bf16)v.y;
    dst[i + 2] = (bf16)v.z;
    dst[i + 3] = (bf16)v.w;
}

// ---------------------------------------------------------------------------
// GEMM core: C[m,n] = sum_k A[m,k] * Bt[n,k]  (both K-contiguous, bf16)
// 128x128 tile, BK=32, 256 threads (4 waves, 2x2 of 64x64), 16x16x32 MFMA.
// ---------------------------------------------------------------------------
#define GEMM_CORE(A_PTR, B_PTR, KDIM)                                          \
    __shared__ bf16 lsA[128 * 32];                                             \
    __shared__ bf16 lsB[128 * 32];                                             \
    const int m0 = blockIdx.x * 128;                                           \
    const int n0 = blockIdx.y * 128;                                           \
    const int t  = threadIdx.x;                                                \
    const int w  = t >> 6, l = t & 63;                                         \
    const int wm = w & 1, wn = w >> 1;                                         \
    const int lr = l & 15, lq = l >> 4;                                        \
    f32x4 acc[4][4] = {};                                                      \
    const bf16* Ab = (A_PTR) + (size_t)(m0 + (t >> 2)) * (KDIM) + (t & 3) * 8; \
    const bf16* Bb = (B_PTR) + (size_t)(n0 + (t >> 2)) * (KDIM) + (t & 3) * 8; \
    bf16* lA = lsA + t * 8;                                                    \
    bf16* lB = lsB + t * 8;                                                    \
    for (int k0 = 0; k0 < (KDIM); k0 += 32) {                                  \
        __syncthreads();                                                       \
        async_copy16(Ab + k0, lA);                                             \
        async_copy16(Ab + (size_t)64 * (KDIM) + k0, lA + 2048);                \
        async_copy16(Bb + k0, lB);                                             \
        async_copy16(Bb + (size_t)64 * (KDIM) + k0, lB + 2048);                \
        __syncthreads();                                                       \
        bf16x8 af[4], bfr[4];                                                  \
        for (int i = 0; i < 4; i++) {                                          \
            af[i]  = *(const bf16x8*)(lsA + (wm * 64 + i * 16 + lr) * 32 + lq * 8); \
            bfr[i] = *(const bf16x8*)(lsB + (wn * 64 + i * 16 + lr) * 32 + lq * 8); \
        }                                                                      \
        for (int i = 0; i < 4; i++)                                            \
            for (int j = 0; j < 4; j++)                                        \
                acc[i][j] = __builtin_amdgcn_mfma_f32_16x16x32_bf16(           \
                    af[i], bfr[j], acc[i][j], 0, 0, 0);                        \
    }

// QKV projection: Xb * Wb^T + b_qkv.
// Q: [B,H,T,64] pre-scaled by 0.125*log2(e) (softmax in base-2);
// K: [B,H,T,64]; V: transposed [B,H,64,T] with keys PERMUTED inside each
// 64-token tile: idx(k) = (r>>2)*16 + kc*4 + (r&3), kc=k>>4, r=k&15 — so a
// single b128 LDS read in attn yields A-frags for two kc blocks.
__launch_bounds__(256)
__global__ void gemm_qkv(const bf16* __restrict__ X, const bf16* __restrict__ W,
                         const float* __restrict__ bias,
                         bf16* __restrict__ Q, bf16* __restrict__ K,
                         bf16* __restrict__ Vt) {
    GEMM_CORE(X, W, 768)
    // epilogue: C/D layout col=lane&15, row=(lane>>4)*4+reg
    for (int i = 0; i < 4; i++) {
        const int rowb = m0 + wm * 64 + i * 16 + lq * 4;
        const int b_ = rowb >> 11, tt = rowb & 2047;   // 128-tiles never straddle batch
        for (int j = 0; j < 4; j++) {
            const int col   = n0 + wn * 64 + j * 16 + lr;
            const int which = col / 768;
            const int rem   = col - which * 768;
            const int h     = rem >> 6, d = rem & 63;
            const float bv  = bias[col];
            if (which == 2) {
                // V^T with in-tile key permutation (tt multiple of 4)
                const int tile = tt >> 6, kl = tt & 63;
                const int kc = kl >> 4, r = kl & 15;
                const int idx = ((r >> 2) << 4) + (kc << 2);   // + (r&3)=0..3
                bf16x4 v4;
                for (int r2 = 0; r2 < 4; r2++) v4[r2] = (bf16)(acc[i][j][r2] + bv);
                *(bf16x4*)(Vt + ((size_t)((b_ * N_H + h) * 64 + d)) * 2048
                           + tile * 64 + idx) = v4;
            } else {
                bf16* dst = (which == 0) ? Q : K;
                const float sc = (which == 0) ? 0.18033688f : 1.0f;  // 1/8 * log2(e)
                for (int r2 = 0; r2 < 4; r2++)
                    dst[(size_t)(((b_ * N_H + h) << 11) + tt + r2) * 64 + d] =
                        (bf16)((acc[i][j][r2] + bv) * sc);
            }
        }
    }
}

// Output projection: Ob[8192x768] * Wpb[768x768]^T + b_proj -> out fp32
__launch_bounds__(256)
__global__ void gemm_proj(const bf16* __restrict__ O, const bf16* __restrict__ W,
                          const float* __restrict__ bias, float* __restrict__ out) {
    GEMM_CORE(O, W, 768)
    for (int i = 0; i < 4; i++) {
        const int rowb = m0 + wm * 64 + i * 16 + lq * 4;
        for (int j = 0; j < 4; j++) {
            const int col  = n0 + wn * 64 + j * 16 + lr;
            const float bv = bias[col];
            for (int r = 0; r < 4; r++)
                out[(size_t)(rowb + r) * 768 + col] = acc[i][j][r] + bv;
        }
    }
}

// ---------------------------------------------------------------------------
// Flash attention, SOFTWARE-PIPELINED: S is computed one tile AHEAD and held
// in registers across the barrier, so each barrier window contains three
// independent chains — exp(i-1) [VALU], PV(i-1) [matrix+LDS], S(i)
// [matrix+LDS] — breaking the S->exp->PV phase lockstep that made the wall
// the SUM of per-phase pipe times (R6/R8/R10 all plateaued ~100us with
// MfmaUtil+VALUBusy ~ 94 summed: alternating phases).
// V is triple-buffered (PV lags S by one tile), K double-buffered: 40KB LDS.
// Geometry: R8's — 512 thr = 8 waves x 16 q = 128 q/block, grid 768
// XCD-swizzled (6 whole heads per XCD -> K/V L2-resident).
// S^T = K Q^T (16x16x32): P^T lands in C-layout == B-operand of 16x16x16.
// O^T = V^T P^T in C-layout; l via ones-MFMA; fixed-shift softmax exp2(s).
// __launch_bounds__(512,6): VGPR<=85 keeps 3 blocks (24 waves) per CU.
// ---------------------------------------------------------------------------
__launch_bounds__(512, 6)
__global__ void attn(const bf16* __restrict__ Q, const bf16* __restrict__ K,
                     const bf16* __restrict__ Vt, bf16* __restrict__ O) {
    __shared__ bf16 lsK[2][64 * 64];
    __shared__ bf16 lsV[3][64 * 64];
    const int bid = blockIdx.x;
    const int xcd = bid & 7, slot = bid >> 3;
    const int bh  = xcd + 8 * (slot >> 4);   // 0..47, 6 heads per XCD
    const int qt  = slot & 15;               // 0..15
    const int t = threadIdx.x, w = t >> 6, l = t & 63;
    const int lr = l & 15, lq = l >> 4;
    const bf16* Qh  = Q  + (size_t)bh * N_T * 64;
    const bf16* Kh  = K  + (size_t)bh * N_T * 64;
    const bf16* Vth = Vt + (size_t)bh * 64 * N_T;
    const int q0 = qt * 128 + w * 16;        // this wave's 16 q rows

    // staging: thread t stages one 16B K chunk + one 16B V chunk per tile.
    const int sr = t >> 3;                   // 0..63
    const int sp = t & 7;                    // 0..7
    const int scn = sp ^ (sr & 7);           // XOR swizzle on source 16B unit

    // Q fragments (B-operand, n=q=lr, k=d)
    bf16x8 qf[2];
    for (int ks = 0; ks < 2; ks++)
        qf[ks] = *(const bf16x8*)(Qh + (size_t)(q0 + lr) * 64 + ks * 32 + lq * 8);

    f32x4 oacc[4] = {};                      // O^T[d = dj*16+lq*4+r][q=lr]
    f32x4 lacc = {};                         // l(q) via ones-MFMA
    const s16x4 ones = {0x3F80, 0x3F80, 0x3F80, 0x3F80};  // bf16 1.0 x4

    // ---- prologue: stage tile 0; barrier; prefetch tile 1; S(0) ----
    async_copy16(Kh  + (size_t)sr * 64 + scn * 8,   lsK[0] + t * 8);
    async_copy16(Vth + (size_t)sr * 2048 + scn * 8, lsV[0] + t * 8);
    __syncthreads();
    async_copy16(Kh  + (size_t)(64 + sr) * 64 + scn * 8, lsK[1] + t * 8);
    async_copy16(Vth + (size_t)sr * 2048 + 64 + scn * 8, lsV[1] + t * 8);

    f32x4 sprev[4] = {};                     // S^T(tile 0)
    for (int ks = 0; ks < 2; ks++)
        for (int ki = 0; ki < 4; ki++) {
            bf16x8 kf = *(const bf16x8*)(lsK[0] + (ki * 16 + lr) * 64
                                         + ((ks * 4 + lq) ^ (lr & 7)) * 8);
            sprev[ki] = __builtin_amdgcn_mfma_f32_16x16x32_bf16(
                kf, qf[ks], sprev[ki], 0, 0, 0);
        }

    int vprev = 0, vcur = 1, vnext = 2;      // V buffer rotation (tiles i-1,i,i+1)

    for (int i = 1; i < 32; i++) {
        __syncthreads();   // tile i staged; all waves done with K(i-1), V(i-2)

        if (i < 31) {      // prefetch tile i+1
            async_copy16(Kh  + (size_t)((i + 1) * 64 + sr) * 64 + scn * 8,
                         lsK[(i + 1) & 1] + t * 8);
            async_copy16(Vth + (size_t)sr * 2048 + (i + 1) * 64 + scn * 8,
                         lsV[vnext] + t * 8);
        }

        // ---- S(i) [matrix+LDS] — independent of exp/PV below ----
        f32x4 snew[4] = {};
        for (int ks = 0; ks < 2; ks++)
            for (int ki = 0; ki < 4; ki++) {
                bf16x8 kf = *(const bf16x8*)(lsK[i & 1] + (ki * 16 + lr) * 64
                                             + ((ks * 4 + lq) ^ (lr & 7)) * 8);
                snew[ki] = __builtin_amdgcn_mfma_f32_16x16x32_bf16(
                    kf, qf[ks], snew[ki], 0, 0, 0);
            }

        // ---- exp(i-1) [VALU] ----
        s16x4 pbf[4];
        for (int ki = 0; ki < 4; ki++) {
            bf16x4 pb;
            for (int r = 0; r < 4; r++)
                pb[r] = (bf16)exp2f(sprev[ki][r]);
            pbf[ki] = __builtin_bit_cast(s16x4, pb);
        }

        // ---- PV(i-1) [matrix+LDS] ----
        const bf16* vb = lsV[vprev];
        for (int c = 0; c < 2; c++)
            for (int dj = 0; dj < 4; dj++) {
                const int unit = (2 * lq + c) ^ (lr & 7);
                s16x8 vv = *(const s16x8*)(vb + (dj * 16 + lr) * 64 + unit * 8);
                s16x4 vlo = __builtin_shufflevector(vv, vv, 0, 1, 2, 3);
                s16x4 vhi = __builtin_shufflevector(vv, vv, 4, 5, 6, 7);
                oacc[dj] = __builtin_amdgcn_mfma_f32_16x16x16bf16_1k(
                    vlo, pbf[2 * c], oacc[dj], 0, 0, 0);
                oacc[dj] = __builtin_amdgcn_mfma_f32_16x16x16bf16_1k(
                    vhi, pbf[2 * c + 1], oacc[dj], 0, 0, 0);
            }
        for (int kc = 0; kc < 4; kc++)
            lacc = __builtin_amdgcn_mfma_f32_16x16x16bf16_1k(
                ones, pbf[kc], lacc, 0, 0, 0);

        // rotate S registers and V buffers
        for (int ki = 0; ki < 4; ki++) sprev[ki] = snew[ki];
        const int tmp = vprev; vprev = vcur; vcur = vnext; vnext = tmp;
    }

    // ---- tail: exp(31) + PV(31) (V(31) in lsV[vprev], no one overwrites) ----
    {
        s16x4 pbf[4];
        for (int ki = 0; ki < 4; ki++) {
            bf16x4 pb;
            for (int r = 0; r < 4; r++)
                pb[r] = (bf16)exp2f(sprev[ki][r]);
            pbf[ki] = __builtin_bit_cast(s16x4, pb);
        }
        const bf16* vb = lsV[vprev];
        for (int c = 0; c < 2; c++)
            for (int dj = 0; dj < 4; dj++) {
                const int unit = (2 * lq + c) ^ (lr & 7);
                s16x8 vv = *(const s16x8*)(vb + (dj * 16 + lr) * 64 + unit * 8);
                s16x4 vlo = __builtin_shufflevector(vv, vv, 0, 1, 2, 3);
                s16x4 vhi = __builtin_shufflevector(vv, vv, 4, 5, 6, 7);
                oacc[dj] = __builtin_amdgcn_mfma_f32_16x16x16bf16_1k(
                    vlo, pbf[2 * c], oacc[dj], 0, 0, 0);
                oacc[dj] = __builtin_amdgcn_mfma_f32_16x16x16bf16_1k(
                    vhi, pbf[2 * c + 1], oacc[dj], 0, 0, 0);
            }
        for (int kc = 0; kc < 4; kc++)
            lacc = __builtin_amdgcn_mfma_f32_16x16x16bf16_1k(
                ones, pbf[kc], lacc, 0, 0, 0);
    }

    // ---- epilogue: O^T/l -> O [B,T,H*64] bf16, 8B packed stores ----
    const int b = bh / N_H, h = bh - b * N_H;
    const float inv_l = 1.0f / lacc[0];      // all regs/lane-quads hold l(q=lr)
    const int tok = q0 + lr;
    bf16* Ob = O + ((size_t)b * N_T + tok) * N_D + h * 64;
    for (int dj = 0; dj < 4; dj++) {
        bf16x4 o4;
        for (int r = 0; r < 4; r++) o4[r] = (bf16)(oacc[dj][r] * inv_l);
        *(bf16x4*)(Ob + dj * 16 + lq * 4) = o4;
    }
}

extern "C" void kernel_launch(void* const* d_in, const int* in_sizes, int n_in,
                              void* d_out, int out_size, void* d_ws, size_t ws_size,
                              hipStream_t stream) {
    const float* x      = (const float*)d_in[0];
    const float* W_qkv  = (const float*)d_in[1];
    const float* b_qkv  = (const float*)d_in[2];
    const float* W_proj = (const float*)d_in[3];
    const float* b_proj = (const float*)d_in[4];
    float* out = (float*)d_out;

    char* ws = (char*)d_ws;
    const size_t n_x  = (size_t)M_TOT * N_D;        // 6291456
    const size_t n_wq = (size_t)3 * N_D * N_D;      // 1769472
    const size_t n_wp = (size_t)N_D * N_D;          // 589824
    const size_t sz_qkv = (size_t)N_B * N_H * N_T * N_DH * sizeof(bf16);  // 12.58 MB

    bf16* xb  = (bf16*)(ws);                 ws += n_x * sizeof(bf16);
    bf16* Wqb = (bf16*)(ws);                 ws += n_wq * sizeof(bf16);
    bf16* Wpb = (bf16*)(ws);                 ws += n_wp * sizeof(bf16);
    bf16* Qb  = (bf16*)(ws);                 ws += sz_qkv;
    bf16* Kb  = (bf16*)(ws);                 ws += sz_qkv;
    bf16* Vtb = (bf16*)(ws);                 ws += sz_qkv;
    bf16* Ob  = (bf16*)(ws);

    dim3 blk(256);
    f2bf3<<<dim3((int)((n_x + n_wq + n_wp) / 1024)), blk, 0, stream>>>(
        x, xb, (int)n_x, W_qkv, Wqb, (int)n_wq, W_proj, Wpb);

    gemm_qkv<<<dim3(M_TOT / 128, 2304 / 128), blk, 0, stream>>>(xb, Wqb, b_qkv, Qb, Kb, Vtb);
    attn<<<dim3(768), dim3(512), 0, stream>>>(Qb, Kb, Vtb, Ob);
    gemm_proj<<<dim3(M_TOT / 128, 768 / 128), blk, 0, stream>>>(Ob, Wpb, b_proj, out);
}